// Round 1
// baseline (741.017 us; speedup 1.0000x reference)
//
#include <hip/hip_runtime.h>

// ---------------------------------------------------------------------------
// Kimi MLA attention block, MI355X (gfx950).
// Pipeline:
//  1) convert hidden_states f32->bf16
//  2) transpose-convert all weights f32(K,N) -> bf16(N,K)  (B^T for gemm_bt)
//  3) q   = hs @ Wq        (bf16 out, 2048x6144)
//  4) ckv = hs @ Wkv_a     (f32 out, 2048x640 padded; cols 576..639 == 0)
//  5) rmsnorm(ckv[:, :512]) -> bf16 (2048x512); rope(ckv[:,512:576]) -> kr
//  6) kv  = ckv_n @ Wkv_b  (bf16, 2048x8192)   [per head: 128 k_pass | 128 v]
//  7) rope on q rot part (in place)
//  8) v transposed per head -> vT (32,128,2048) for clean LDS staging
//  9) causal flash attention (16x16x32 bf16 MFMA, fp32 online softmax)
// 10) out = attn @ Wo      (f32 out -> d_out)
// positions input is arange(SEQ) by construction; row index is used directly.
// ---------------------------------------------------------------------------

typedef __bf16 bf16x8 __attribute__((ext_vector_type(8)));
typedef float f32x4 __attribute__((ext_vector_type(4)));

#define SEQLEN 2048
#define NH 32
#define QH 192
#define QN 6144   // NH*QH
#define KVN 8192  // NH*256
#define HID 4096
#define CKVP 640  // padded 512+64 -> 640

__device__ __forceinline__ unsigned short f2b(float f) {
  union { float f; unsigned int u; } x; x.f = f;
  unsigned int r = (x.u + 0x7FFFu + ((x.u >> 16) & 1u)) >> 16;
  return (unsigned short)r;
}
__device__ __forceinline__ float b2f(unsigned short b) {
  union { unsigned int u; float f; } x; x.u = ((unsigned int)b) << 16;
  return x.f;
}

// ---- elementwise f32 -> bf16 (vectorized) ----
__global__ __launch_bounds__(256) void convk(const float* __restrict__ in,
                                             unsigned short* __restrict__ out,
                                             int n4) {
  int i = blockIdx.x * 256 + threadIdx.x;
  if (i < n4) {
    float4 v = ((const float4*)in)[i];
    ushort4 o;
    o.x = f2b(v.x); o.y = f2b(v.y); o.z = f2b(v.z); o.w = f2b(v.w);
    ((ushort4*)out)[i] = o;
  }
}

// ---- transpose+convert: out[c][r] = bf16(in[r][c]) for c<Cin else 0; out is Cp x R ----
__global__ __launch_bounds__(256) void tconv(const float* __restrict__ in,
                                             unsigned short* __restrict__ out,
                                             int R, int Cin, int Cp) {
  __shared__ float t[64][65];
  const int r0 = blockIdx.x * 64, c0 = blockIdx.y * 64;
  const int tid = threadIdx.x;
#pragma unroll
  for (int i = 0; i < 16; ++i) {
    int idx = tid + i * 256;
    int rr = idx >> 6, cc = idx & 63;
    int c = c0 + cc;
    t[rr][cc] = (c < Cin) ? in[(size_t)(r0 + rr) * Cin + c] : 0.f;
  }
  __syncthreads();
#pragma unroll
  for (int i = 0; i < 16; ++i) {
    int idx = tid + i * 256;
    int cc = idx >> 6, rr = idx & 63;
    out[(size_t)(c0 + cc) * R + (r0 + rr)] = f2b(t[rr][cc]);
  }
}

// ---- GEMM: C[M,N] = A[M,K] * B[N,K]^T, bf16 in, fp32 acc (m97 structure) ----
template <typename OutT>
__global__ __launch_bounds__(256) void gemm_bt(const unsigned short* __restrict__ A,
                                               const unsigned short* __restrict__ B,
                                               OutT* __restrict__ C,
                                               int M, int N, int K) {
  __shared__ __align__(16) unsigned short As[128 * 64];
  __shared__ __align__(16) unsigned short Bs[128 * 64];
  const int tid = threadIdx.x;
  const int lane = tid & 63;
  const int w = tid >> 6;
  const int wr = w >> 1, wc = w & 1;
  const int l15 = lane & 15, lg = lane >> 4;
  const int ntn = N >> 7;
  const int bm = blockIdx.x / ntn, bn = blockIdx.x % ntn;
  const int m0 = bm << 7, n0 = bn << 7;
  const int lrow = tid >> 3;
  const int lcol = (tid & 7) << 3;

  const f32x4 zero4 = {0.f, 0.f, 0.f, 0.f};
  f32x4 acc[4][4];
#pragma unroll
  for (int i = 0; i < 4; ++i)
#pragma unroll
    for (int j = 0; j < 4; ++j) acc[i][j] = zero4;

  for (int k0 = 0; k0 < K; k0 += 64) {
#pragma unroll
    for (int j = 0; j < 4; ++j) {
      const unsigned short* ga = A + (size_t)(m0 + j * 32 + lrow) * K + (k0 + lcol);
      const unsigned short* gb = B + (size_t)(n0 + j * 32 + lrow) * K + (k0 + lcol);
      __builtin_amdgcn_global_load_lds(
          (const __attribute__((address_space(1))) void*)ga,
          (__attribute__((address_space(3))) void*)(&As[j * 2048 + w * 512]), 16, 0, 0);
      __builtin_amdgcn_global_load_lds(
          (const __attribute__((address_space(1))) void*)gb,
          (__attribute__((address_space(3))) void*)(&Bs[j * 2048 + w * 512]), 16, 0, 0);
    }
    __syncthreads();  // drains vmcnt before barrier
#pragma unroll
    for (int kk = 0; kk < 2; ++kk) {
      bf16x8 a[4], b[4];
#pragma unroll
      for (int m = 0; m < 4; ++m)
        a[m] = *(const bf16x8*)&As[(wr * 64 + m * 16 + l15) * 64 + kk * 32 + lg * 8];
#pragma unroll
      for (int n = 0; n < 4; ++n)
        b[n] = *(const bf16x8*)&Bs[(wc * 64 + n * 16 + l15) * 64 + kk * 32 + lg * 8];
#pragma unroll
      for (int m = 0; m < 4; ++m)
#pragma unroll
        for (int n = 0; n < 4; ++n)
          acc[m][n] = __builtin_amdgcn_mfma_f32_16x16x32_bf16(a[m], b[n], acc[m][n], 0, 0, 0);
    }
    __syncthreads();
  }
  // epilogue; C/D layout: col = lane&15, row = (lane>>4)*4 + i   [m89-verified]
  const int r0 = m0 + wr * 64, c0 = n0 + wc * 64;
#pragma unroll
  for (int m = 0; m < 4; ++m)
#pragma unroll
    for (int n = 0; n < 4; ++n) {
      int r = r0 + m * 16 + lg * 4;
      int c = c0 + n * 16 + l15;
#pragma unroll
      for (int i = 0; i < 4; ++i) {
        float v = acc[m][n][i];
        if constexpr (sizeof(OutT) == 2)
          ((unsigned short*)C)[(size_t)(r + i) * N + c] = f2b(v);
        else
          ((float*)C)[(size_t)(r + i) * N + c] = v;
      }
    }
}

// ---- RMSNorm over ckv[:, :512] -> bf16 ----
__global__ __launch_bounds__(256) void rmsnorm_k(const float* __restrict__ ckv,
                                                 const float* __restrict__ w,
                                                 unsigned short* __restrict__ out) {
  const int s = blockIdx.x;
  const int tid = threadIdx.x;
  const float* row = ckv + (size_t)s * CKVP;
  float x0 = row[tid], x1 = row[tid + 256];
  float ss = x0 * x0 + x1 * x1;
#pragma unroll
  for (int o = 1; o < 64; o <<= 1) ss += __shfl_xor(ss, o, 64);
  __shared__ float red[4];
  if ((tid & 63) == 0) red[tid >> 6] = ss;
  __syncthreads();
  float rs = rsqrtf((red[0] + red[1] + red[2] + red[3]) * (1.f / 512.f) + 1e-6f);
  out[(size_t)s * 512 + tid] = f2b(w[tid] * x0 * rs);
  out[(size_t)s * 512 + tid + 256] = f2b(w[tid + 256] * x1 * rs);
}

// ---- RoPE on q rot part (in place, bf16) ----
__global__ __launch_bounds__(256) void rope_q_k(unsigned short* __restrict__ q) {
  int idx = blockIdx.x * 256 + threadIdx.x;  // 2048*32*32
  int i = idx & 31, h = (idx >> 5) & 31, s = idx >> 10;
  float inv = exp2f(-(float)i * 0.4152410118609203f);  // 10000^(-i/32)
  float ang = (float)s * inv;
  float c = cosf(ang), sn = sinf(ang);
  size_t base = (size_t)s * QN + h * QH + 128;
  float x1 = b2f(q[base + i]), x2 = b2f(q[base + 32 + i]);
  q[base + i] = f2b(x1 * c - x2 * sn);
  q[base + 32 + i] = f2b(x2 * c + x1 * sn);
}

// ---- RoPE on shared k rot part (f32 src) -> kr bf16 (2048x64) ----
__global__ __launch_bounds__(256) void rope_k_k(const float* __restrict__ ckv,
                                                unsigned short* __restrict__ kr) {
  int idx = blockIdx.x * 256 + threadIdx.x;  // 2048*32
  int i = idx & 31, s = idx >> 5;
  float inv = exp2f(-(float)i * 0.4152410118609203f);
  float ang = (float)s * inv;
  float c = cosf(ang), sn = sinf(ang);
  const float* row = ckv + (size_t)s * CKVP + 512;
  float x1 = row[i], x2 = row[32 + i];
  kr[(size_t)s * 64 + i] = f2b(x1 * c - x2 * sn);
  kr[(size_t)s * 64 + 32 + i] = f2b(x2 * c + x1 * sn);
}

// ---- per-head V transpose: vT[h][v][t] = kv[t][h*256+128+v] ----
__global__ __launch_bounds__(256) void tv_k(const unsigned short* __restrict__ kv,
                                            unsigned short* __restrict__ vT) {
  __shared__ unsigned short t[64][66];
  const int t0 = blockIdx.x * 64, v0 = blockIdx.y * 64, h = blockIdx.z;
  const int tid = threadIdx.x;
#pragma unroll
  for (int i = 0; i < 16; ++i) {
    int idx = tid + i * 256;
    int rr = idx >> 6, cc = idx & 63;
    t[rr][cc] = kv[(size_t)(t0 + rr) * KVN + h * 256 + 128 + v0 + cc];
  }
  __syncthreads();
#pragma unroll
  for (int i = 0; i < 16; ++i) {
    int idx = tid + i * 256;
    int cc = idx >> 6, rr = idx & 63;
    vT[((size_t)h * 128 + v0 + cc) * SEQLEN + t0 + rr] = t[rr][cc];
  }
}

// ---- causal flash attention ----
// block = (64 q rows of one head), 4 waves x 16 rows; KV tile = 64
__global__ __launch_bounds__(256) void attn_k(const unsigned short* __restrict__ q,
                                              const unsigned short* __restrict__ kv,
                                              const unsigned short* __restrict__ kr,
                                              const unsigned short* __restrict__ vT,
                                              unsigned short* __restrict__ ao) {
  __shared__ __align__(16) unsigned short Kt[64 * 200];   // row stride 200 (2-way bank)
  __shared__ __align__(16) unsigned short Vt[128 * 72];   // V^T tile [v][t], stride 72
  __shared__ __align__(16) unsigned short Pl[4][16 * 72]; // per-wave P [q][t], stride 72

  const int qb = (int)gridDim.x - 1 - (int)blockIdx.x;  // heavy blocks first
  const int h = blockIdx.y;
  const int tid = threadIdx.x;
  const int lane = tid & 63;
  const int w = tid >> 6;
  const int l15 = lane & 15, lg = lane >> 4;
  const int qrow_base = qb * 64 + w * 16;
  const float scale = 0.07216878364870323f;  // 192^-0.5

  // Q fragments: rows l15, d = c*32 + lg*8 .. +8
  bf16x8 qf[6];
  {
    const size_t qoff = (size_t)(qrow_base + l15) * QN + (size_t)h * QH + lg * 8;
#pragma unroll
    for (int c = 0; c < 6; ++c) qf[c] = *(const bf16x8*)(q + qoff + c * 32);
  }

  const f32x4 zero4 = {0.f, 0.f, 0.f, 0.f};
  f32x4 o[8];
#pragma unroll
  for (int i = 0; i < 8; ++i) o[i] = zero4;
  float m_r[4], s_r[4];
#pragma unroll
  for (int i = 0; i < 4; ++i) { m_r[i] = -1e30f; s_r[i] = 0.f; }

  for (int it = 0; it <= qb; ++it) {
    const int t0 = it * 64;
    // stage K tile: k_pass (cols 0..127) + shared rot (cols 128..191)
#pragma unroll
    for (int p = 0; p < 4; ++p) {
      int id = tid + p * 256;
      int r = id >> 4, cc = (id & 15) * 8;
      *(bf16x8*)&Kt[r * 200 + cc] =
          *(const bf16x8*)&kv[(size_t)(t0 + r) * KVN + h * 256 + cc];
    }
#pragma unroll
    for (int p = 0; p < 2; ++p) {
      int id = tid + p * 256;
      int r = id >> 3, cc = (id & 7) * 8;
      *(bf16x8*)&Kt[r * 200 + 128 + cc] = *(const bf16x8*)&kr[(size_t)(t0 + r) * 64 + cc];
    }
    // stage V^T tile
#pragma unroll
    for (int p = 0; p < 4; ++p) {
      int id = tid + p * 256;
      int v = id >> 3, cc = (id & 7) * 8;
      *(bf16x8*)&Vt[v * 72 + cc] =
          *(const bf16x8*)&vT[((size_t)h * 128 + v) * SEQLEN + t0 + cc];
    }
    __syncthreads();

    // QK^T: D[q][t], row q=(lg*4+i), col t=l15 per 16-wide t-tile
    f32x4 st[4];
#pragma unroll
    for (int tt = 0; tt < 4; ++tt) {
      f32x4 c4 = zero4;
#pragma unroll
      for (int c = 0; c < 6; ++c) {
        bf16x8 kf = *(const bf16x8*)&Kt[(tt * 16 + l15) * 200 + c * 32 + lg * 8];
        c4 = __builtin_amdgcn_mfma_f32_16x16x32_bf16(qf[c], kf, c4, 0, 0, 0);
      }
      st[tt] = c4;
    }
    // scale + causal mask + tile row-max
    float mt[4];
#pragma unroll
    for (int i = 0; i < 4; ++i) mt[i] = -1e30f;
#pragma unroll
    for (int tt = 0; tt < 4; ++tt) {
      int tg = t0 + tt * 16 + l15;
#pragma unroll
      for (int i = 0; i < 4; ++i) {
        int qg = qrow_base + lg * 4 + i;
        float v = st[tt][i] * scale;
        v = (tg > qg) ? -1e30f : v;
        st[tt][i] = v;
        mt[i] = fmaxf(mt[i], v);
      }
    }
#pragma unroll
    for (int off = 1; off < 16; off <<= 1)
#pragma unroll
      for (int i = 0; i < 4; ++i) mt[i] = fmaxf(mt[i], __shfl_xor(mt[i], off, 64));

    float al[4], ps[4];
#pragma unroll
    for (int i = 0; i < 4; ++i) {
      float mn = fmaxf(m_r[i], mt[i]);
      al[i] = __expf(m_r[i] - mn);
      m_r[i] = mn;
      ps[i] = 0.f;
    }
#pragma unroll
    for (int tt = 0; tt < 4; ++tt)
#pragma unroll
      for (int i = 0; i < 4; ++i) {
        float p = __expf(st[tt][i] - m_r[i]);
        st[tt][i] = p;
        ps[i] += p;
      }
#pragma unroll
    for (int off = 1; off < 16; off <<= 1)
#pragma unroll
      for (int i = 0; i < 4; ++i) ps[i] += __shfl_xor(ps[i], off, 64);
#pragma unroll
    for (int i = 0; i < 4; ++i) s_r[i] = s_r[i] * al[i] + ps[i];

    // write P (bf16) to per-wave LDS in [q][t] layout for the PV A-operand
#pragma unroll
    for (int tt = 0; tt < 4; ++tt)
#pragma unroll
      for (int i = 0; i < 4; ++i)
        Pl[w][(lg * 4 + i) * 72 + tt * 16 + l15] = f2b(st[tt][i]);

    // rescale O
#pragma unroll
    for (int vt = 0; vt < 8; ++vt)
#pragma unroll
      for (int i = 0; i < 4; ++i) o[vt][i] *= al[i];

    __syncthreads();  // P visible (cross-lane)

    // PV: A = P[q][t], B = V[t][v] (from Vt = V^T[v][t])
    bf16x8 pa0 = *(const bf16x8*)&Pl[w][l15 * 72 + lg * 8];
    bf16x8 pa1 = *(const bf16x8*)&Pl[w][l15 * 72 + 32 + lg * 8];
#pragma unroll
    for (int vt = 0; vt < 8; ++vt) {
      bf16x8 b0 = *(const bf16x8*)&Vt[(vt * 16 + l15) * 72 + lg * 8];
      bf16x8 b1 = *(const bf16x8*)&Vt[(vt * 16 + l15) * 72 + 32 + lg * 8];
      o[vt] = __builtin_amdgcn_mfma_f32_16x16x32_bf16(pa0, b0, o[vt], 0, 0, 0);
      o[vt] = __builtin_amdgcn_mfma_f32_16x16x32_bf16(pa1, b1, o[vt], 0, 0, 0);
    }
    __syncthreads();  // LDS consumed; safe to restage next tile
  }

  // normalize + store
#pragma unroll
  for (int vt = 0; vt < 8; ++vt)
#pragma unroll
    for (int i = 0; i < 4; ++i) {
      int qg = qrow_base + lg * 4 + i;
      int col = h * 128 + vt * 16 + l15;
      ao[(size_t)qg * (NH * 128) + col] = f2b(o[vt][i] / s_r[i]);
    }
}

extern "C" void kernel_launch(void* const* d_in, const int* in_sizes, int n_in,
                              void* d_out, int out_size, void* d_ws, size_t ws_size,
                              hipStream_t stream) {
  (void)in_sizes; (void)n_in; (void)out_size; (void)ws_size;
  // inputs: 0=positions(arange, unused), 1=hidden_states, 2=Wq, 3=Wkv_a, 4=ln_w, 5=Wkv_b, 6=Wo
  const float* hs = (const float*)d_in[1];
  const float* Wq = (const float*)d_in[2];
  const float* Wkva = (const float*)d_in[3];
  const float* lnw = (const float*)d_in[4];
  const float* Wkvb = (const float*)d_in[5];
  const float* Wo = (const float*)d_in[6];
  float* out = (float*)d_out;
  char* ws = (char*)d_ws;

  constexpr size_t OFF_HSBF = 0;                                    // 2048x4096 bf16
  constexpr size_t OFF_WQT = OFF_HSBF + (size_t)2048 * 4096 * 2;    // 6144x4096 bf16
  constexpr size_t OFF_WKVAT = OFF_WQT + (size_t)6144 * 4096 * 2;   // 640x4096 bf16
  constexpr size_t OFF_WKVBT = OFF_WKVAT + (size_t)640 * 4096 * 2;  // 8192x512 bf16
  constexpr size_t OFF_WOT = OFF_WKVBT + (size_t)8192 * 512 * 2;    // 4096x4096 bf16
  constexpr size_t OFF_Q = OFF_WOT + (size_t)4096 * 4096 * 2;       // 2048x6144 bf16
  constexpr size_t OFF_CKV = OFF_Q + (size_t)2048 * 6144 * 2;       // 2048x640 f32
  constexpr size_t OFF_CKVN = OFF_CKV + (size_t)2048 * 640 * 4;     // 2048x512 bf16
  constexpr size_t OFF_KR = OFF_CKVN + (size_t)2048 * 512 * 2;      // 2048x64 bf16
  constexpr size_t OFF_KV = OFF_KR + (size_t)2048 * 64 * 2;         // 2048x8192 bf16
  constexpr size_t OFF_VT = OFF_KV + (size_t)2048 * 8192 * 2;       // 32x128x2048 bf16
  constexpr size_t OFF_AO = OFF_VT + (size_t)32 * 128 * 2048 * 2;   // 2048x4096 bf16
  // total ~214 MB

  unsigned short* hs_bf = (unsigned short*)(ws + OFF_HSBF);
  unsigned short* WqT = (unsigned short*)(ws + OFF_WQT);
  unsigned short* WkvaT = (unsigned short*)(ws + OFF_WKVAT);
  unsigned short* WkvbT = (unsigned short*)(ws + OFF_WKVBT);
  unsigned short* WoT = (unsigned short*)(ws + OFF_WOT);
  unsigned short* qbuf = (unsigned short*)(ws + OFF_Q);
  float* ckv = (float*)(ws + OFF_CKV);
  unsigned short* ckvn = (unsigned short*)(ws + OFF_CKVN);
  unsigned short* kr = (unsigned short*)(ws + OFF_KR);
  unsigned short* kvbuf = (unsigned short*)(ws + OFF_KV);
  unsigned short* vT = (unsigned short*)(ws + OFF_VT);
  unsigned short* ao = (unsigned short*)(ws + OFF_AO);

  convk<<<dim3(8192), 256, 0, stream>>>(hs, hs_bf, 2048 * 4096 / 4);
  tconv<<<dim3(64, 96), 256, 0, stream>>>(Wq, WqT, 4096, 6144, 6144);
  tconv<<<dim3(64, 10), 256, 0, stream>>>(Wkva, WkvaT, 4096, 576, 640);
  tconv<<<dim3(8, 128), 256, 0, stream>>>(Wkvb, WkvbT, 512, 8192, 8192);
  tconv<<<dim3(64, 64), 256, 0, stream>>>(Wo, WoT, 4096, 4096, 4096);

  gemm_bt<unsigned short><<<dim3(16 * 48), 256, 0, stream>>>(hs_bf, WqT, qbuf, 2048, 6144, 4096);
  gemm_bt<float><<<dim3(16 * 5), 256, 0, stream>>>(hs_bf, WkvaT, ckv, 2048, 640, 4096);
  rmsnorm_k<<<dim3(2048), 256, 0, stream>>>(ckv, lnw, ckvn);
  rope_k_k<<<dim3(256), 256, 0, stream>>>(ckv, kr);
  gemm_bt<unsigned short><<<dim3(16 * 64), 256, 0, stream>>>(ckvn, WkvbT, kvbuf, 2048, 8192, 512);
  rope_q_k<<<dim3(8192), 256, 0, stream>>>(qbuf);
  tv_k<<<dim3(32, 2, 32), 256, 0, stream>>>(kvbuf, vT);
  attn_k<<<dim3(32, 32), 256, 0, stream>>>(qbuf, kvbuf, kr, vT, ao);
  gemm_bt<float><<<dim3(16 * 32), 256, 0, stream>>>(ao, WoT, out, 2048, 4096, 4096);
}

// Round 2
// 693.066 us; speedup vs baseline: 1.0692x; 1.0692x over previous
//
#include <hip/hip_runtime.h>

// ---------------------------------------------------------------------------
// Kimi MLA attention block, MI355X (gfx950).  Round 2: attn_k rebuilt —
// async reg-staged K/V (T14), paired causal tiles (perfect balance),
// 32 q-rows/wave, XOR-swizzled K LDS (T2), setprio around MFMA (T5).
// ---------------------------------------------------------------------------

typedef __bf16 bf16x8 __attribute__((ext_vector_type(8)));
typedef float f32x4 __attribute__((ext_vector_type(4)));

#define SEQLEN 2048
#define NH 32
#define QH 192
#define QN 6144   // NH*QH
#define KVN 8192  // NH*256
#define HID 4096
#define CKVP 640  // padded 512+64 -> 640

__device__ __forceinline__ unsigned short f2b(float f) {
  union { float f; unsigned int u; } x; x.f = f;
  unsigned int r = (x.u + 0x7FFFu + ((x.u >> 16) & 1u)) >> 16;
  return (unsigned short)r;
}
__device__ __forceinline__ float b2f(unsigned short b) {
  union { unsigned int u; float f; } x; x.u = ((unsigned int)b) << 16;
  return x.f;
}

// ---- elementwise f32 -> bf16 (vectorized) ----
__global__ __launch_bounds__(256) void convk(const float* __restrict__ in,
                                             unsigned short* __restrict__ out,
                                             int n4) {
  int i = blockIdx.x * 256 + threadIdx.x;
  if (i < n4) {
    float4 v = ((const float4*)in)[i];
    ushort4 o;
    o.x = f2b(v.x); o.y = f2b(v.y); o.z = f2b(v.z); o.w = f2b(v.w);
    ((ushort4*)out)[i] = o;
  }
}

// ---- transpose+convert: out[c][r] = bf16(in[r][c]) for c<Cin else 0; out is Cp x R ----
__global__ __launch_bounds__(256) void tconv(const float* __restrict__ in,
                                             unsigned short* __restrict__ out,
                                             int R, int Cin, int Cp) {
  __shared__ float t[64][65];
  const int r0 = blockIdx.x * 64, c0 = blockIdx.y * 64;
  const int tid = threadIdx.x;
#pragma unroll
  for (int i = 0; i < 16; ++i) {
    int idx = tid + i * 256;
    int rr = idx >> 6, cc = idx & 63;
    int c = c0 + cc;
    t[rr][cc] = (c < Cin) ? in[(size_t)(r0 + rr) * Cin + c] : 0.f;
  }
  __syncthreads();
#pragma unroll
  for (int i = 0; i < 16; ++i) {
    int idx = tid + i * 256;
    int cc = idx >> 6, rr = idx & 63;
    out[(size_t)(c0 + cc) * R + (r0 + rr)] = f2b(t[rr][cc]);
  }
}

// ---- GEMM: C[M,N] = A[M,K] * B[N,K]^T, bf16 in, fp32 acc (m97 structure) ----
template <typename OutT>
__global__ __launch_bounds__(256) void gemm_bt(const unsigned short* __restrict__ A,
                                               const unsigned short* __restrict__ B,
                                               OutT* __restrict__ C,
                                               int M, int N, int K) {
  __shared__ __align__(16) unsigned short As[128 * 64];
  __shared__ __align__(16) unsigned short Bs[128 * 64];
  const int tid = threadIdx.x;
  const int lane = tid & 63;
  const int w = tid >> 6;
  const int wr = w >> 1, wc = w & 1;
  const int l15 = lane & 15, lg = lane >> 4;
  const int ntn = N >> 7;
  const int bm = blockIdx.x / ntn, bn = blockIdx.x % ntn;
  const int m0 = bm << 7, n0 = bn << 7;
  const int lrow = tid >> 3;
  const int lcol = (tid & 7) << 3;

  const f32x4 zero4 = {0.f, 0.f, 0.f, 0.f};
  f32x4 acc[4][4];
#pragma unroll
  for (int i = 0; i < 4; ++i)
#pragma unroll
    for (int j = 0; j < 4; ++j) acc[i][j] = zero4;

  for (int k0 = 0; k0 < K; k0 += 64) {
#pragma unroll
    for (int j = 0; j < 4; ++j) {
      const unsigned short* ga = A + (size_t)(m0 + j * 32 + lrow) * K + (k0 + lcol);
      const unsigned short* gb = B + (size_t)(n0 + j * 32 + lrow) * K + (k0 + lcol);
      __builtin_amdgcn_global_load_lds(
          (const __attribute__((address_space(1))) void*)ga,
          (__attribute__((address_space(3))) void*)(&As[j * 2048 + w * 512]), 16, 0, 0);
      __builtin_amdgcn_global_load_lds(
          (const __attribute__((address_space(1))) void*)gb,
          (__attribute__((address_space(3))) void*)(&Bs[j * 2048 + w * 512]), 16, 0, 0);
    }
    __syncthreads();  // drains vmcnt before barrier
#pragma unroll
    for (int kk = 0; kk < 2; ++kk) {
      bf16x8 a[4], b[4];
#pragma unroll
      for (int m = 0; m < 4; ++m)
        a[m] = *(const bf16x8*)&As[(wr * 64 + m * 16 + l15) * 64 + kk * 32 + lg * 8];
#pragma unroll
      for (int n = 0; n < 4; ++n)
        b[n] = *(const bf16x8*)&Bs[(wc * 64 + n * 16 + l15) * 64 + kk * 32 + lg * 8];
#pragma unroll
      for (int m = 0; m < 4; ++m)
#pragma unroll
        for (int n = 0; n < 4; ++n)
          acc[m][n] = __builtin_amdgcn_mfma_f32_16x16x32_bf16(a[m], b[n], acc[m][n], 0, 0, 0);
    }
    __syncthreads();
  }
  // epilogue; C/D layout: col = lane&15, row = (lane>>4)*4 + i   [m89-verified]
  const int r0 = m0 + wr * 64, c0 = n0 + wc * 64;
#pragma unroll
  for (int m = 0; m < 4; ++m)
#pragma unroll
    for (int n = 0; n < 4; ++n) {
      int r = r0 + m * 16 + lg * 4;
      int c = c0 + n * 16 + l15;
#pragma unroll
      for (int i = 0; i < 4; ++i) {
        float v = acc[m][n][i];
        if constexpr (sizeof(OutT) == 2)
          ((unsigned short*)C)[(size_t)(r + i) * N + c] = f2b(v);
        else
          ((float*)C)[(size_t)(r + i) * N + c] = v;
      }
    }
}

// ---- RMSNorm over ckv[:, :512] -> bf16 ----
__global__ __launch_bounds__(256) void rmsnorm_k(const float* __restrict__ ckv,
                                                 const float* __restrict__ w,
                                                 unsigned short* __restrict__ out) {
  const int s = blockIdx.x;
  const int tid = threadIdx.x;
  const float* row = ckv + (size_t)s * CKVP;
  float x0 = row[tid], x1 = row[tid + 256];
  float ss = x0 * x0 + x1 * x1;
#pragma unroll
  for (int o = 1; o < 64; o <<= 1) ss += __shfl_xor(ss, o, 64);
  __shared__ float red[4];
  if ((tid & 63) == 0) red[tid >> 6] = ss;
  __syncthreads();
  float rs = rsqrtf((red[0] + red[1] + red[2] + red[3]) * (1.f / 512.f) + 1e-6f);
  out[(size_t)s * 512 + tid] = f2b(w[tid] * x0 * rs);
  out[(size_t)s * 512 + tid + 256] = f2b(w[tid + 256] * x1 * rs);
}

// ---- RoPE on q rot part (in place, bf16) ----
__global__ __launch_bounds__(256) void rope_q_k(unsigned short* __restrict__ q) {
  int idx = blockIdx.x * 256 + threadIdx.x;  // 2048*32*32
  int i = idx & 31, h = (idx >> 5) & 31, s = idx >> 10;
  float inv = exp2f(-(float)i * 0.4152410118609203f);  // 10000^(-i/32)
  float ang = (float)s * inv;
  float c = cosf(ang), sn = sinf(ang);
  size_t base = (size_t)s * QN + h * QH + 128;
  float x1 = b2f(q[base + i]), x2 = b2f(q[base + 32 + i]);
  q[base + i] = f2b(x1 * c - x2 * sn);
  q[base + 32 + i] = f2b(x2 * c + x1 * sn);
}

// ---- RoPE on shared k rot part (f32 src) -> kr bf16 (2048x64) ----
__global__ __launch_bounds__(256) void rope_k_k(const float* __restrict__ ckv,
                                                unsigned short* __restrict__ kr) {
  int idx = blockIdx.x * 256 + threadIdx.x;  // 2048*32
  int i = idx & 31, s = idx >> 5;
  float inv = exp2f(-(float)i * 0.4152410118609203f);
  float ang = (float)s * inv;
  float c = cosf(ang), sn = sinf(ang);
  const float* row = ckv + (size_t)s * CKVP + 512;
  float x1 = row[i], x2 = row[32 + i];
  kr[(size_t)s * 64 + i] = f2b(x1 * c - x2 * sn);
  kr[(size_t)s * 64 + 32 + i] = f2b(x2 * c + x1 * sn);
}

// ---- per-head V transpose: vT[h][v][t] = kv[t][h*256+128+v] ----
__global__ __launch_bounds__(256) void tv_k(const unsigned short* __restrict__ kv,
                                            unsigned short* __restrict__ vT) {
  __shared__ unsigned short t[64][66];
  const int t0 = blockIdx.x * 64, v0 = blockIdx.y * 64, h = blockIdx.z;
  const int tid = threadIdx.x;
#pragma unroll
  for (int i = 0; i < 16; ++i) {
    int idx = tid + i * 256;
    int rr = idx >> 6, cc = idx & 63;
    t[rr][cc] = kv[(size_t)(t0 + rr) * KVN + h * 256 + 128 + v0 + cc];
  }
  __syncthreads();
#pragma unroll
  for (int i = 0; i < 16; ++i) {
    int idx = tid + i * 256;
    int cc = idx >> 6, rr = idx & 63;
    vT[((size_t)h * 128 + v0 + cc) * SEQLEN + t0 + rr] = t[rr][cc];
  }
}

// ---- causal flash attention, round-2 structure ----
// grid (8, 32): block bx handles q-tiles {bx, 15-bx} (128 rows each) of head
// blockIdx.y. 4 waves x 32 q-rows. KV tile = 64, async reg-staged.
// Every block does exactly (2*bx+2) + (2*(15-bx)+2) = 36 KV iterations.
__global__ __launch_bounds__(256) void attn_k(const unsigned short* __restrict__ q,
                                              const unsigned short* __restrict__ kv,
                                              const unsigned short* __restrict__ kr,
                                              const unsigned short* __restrict__ vT,
                                              unsigned short* __restrict__ ao) {
  // Kt rows: 192 ushorts = 384 B (=3*128 -> row base bank-invariant);
  // 16B slots XOR-swizzled by row&7 -> <=2-way on write and read (free).
  __shared__ __align__(16) unsigned short Kt[64 * 192];   // 24 KB
  __shared__ __align__(16) unsigned short Vt[128 * 72];   // 18 KB
  __shared__ __align__(16) unsigned short Pl[4][32 * 72]; // 18 KB (per-wave)

  const int tid = threadIdx.x;
  const int lane = tid & 63;
  const int w = tid >> 6;
  const int l15 = lane & 15, lg = lane >> 4;
  const int sw = l15 & 7;
  const int h = blockIdx.y;
  const float scale = 0.07216878364870323f;  // 192^-0.5
  const f32x4 zero4 = {0.f, 0.f, 0.f, 0.f};

  bf16x8 kregs[4], rregs[2], vregs[4];

  auto loadregs = [&](int t0) {
#pragma unroll
    for (int p = 0; p < 4; ++p) {
      int id = tid + p * 256;
      kregs[p] = *(const bf16x8*)&kv[(size_t)(t0 + (id >> 4)) * KVN + h * 256 + (id & 15) * 8];
    }
#pragma unroll
    for (int p = 0; p < 2; ++p) {
      int id = tid + p * 256;
      rregs[p] = *(const bf16x8*)&kr[(size_t)(t0 + (id >> 3)) * 64 + (id & 7) * 8];
    }
#pragma unroll
    for (int p = 0; p < 4; ++p) {
      int id = tid + p * 256;
      vregs[p] = *(const bf16x8*)&vT[((size_t)h * 128 + (id >> 3)) * SEQLEN + t0 + (id & 7) * 8];
    }
  };
  auto writelds = [&]() {
#pragma unroll
    for (int p = 0; p < 4; ++p) {
      int id = tid + p * 256;
      int r = id >> 4, c16 = id & 15;
      *(bf16x8*)&Kt[r * 192 + ((c16 ^ (r & 7)) << 3)] = kregs[p];
    }
#pragma unroll
    for (int p = 0; p < 2; ++p) {
      int id = tid + p * 256;
      int r = id >> 3;
      *(bf16x8*)&Kt[r * 192 + ((16 + ((id & 7) ^ (r & 7))) << 3)] = rregs[p];
    }
#pragma unroll
    for (int p = 0; p < 4; ++p) {
      int id = tid + p * 256;
      *(bf16x8*)&Vt[(id >> 3) * 72 + (id & 7) * 8] = vregs[p];
    }
  };

#pragma unroll 1
  for (int pass = 0; pass < 2; ++pass) {
    const int qt = pass ? (15 - (int)blockIdx.x) : (int)blockIdx.x;
    const int n_it = 2 * qt + 2;
    const int qrow_base = qt * 128 + w * 32;

    // Q fragments (rows m*16+l15, d = c*32 + lg*8)
    bf16x8 qf[2][6];
#pragma unroll
    for (int m = 0; m < 2; ++m) {
      const size_t qoff = (size_t)(qrow_base + m * 16 + l15) * QN + (size_t)h * QH + lg * 8;
#pragma unroll
      for (int c = 0; c < 6; ++c) qf[m][c] = *(const bf16x8*)(q + qoff + c * 32);
    }

    f32x4 o[2][8];
    float m_r[2][4], s_r[2][4];
#pragma unroll
    for (int m = 0; m < 2; ++m) {
#pragma unroll
      for (int vt = 0; vt < 8; ++vt) o[m][vt] = zero4;
#pragma unroll
      for (int i = 0; i < 4; ++i) { m_r[m][i] = -1e30f; s_r[m][i] = 0.f; }
    }

    loadregs(0);

#pragma unroll 1
    for (int it = 0; it < n_it; ++it) {
      const int t0 = it * 64;
      writelds();                      // vmcnt waits land here (loads issued last iter)
      __syncthreads();                 // tile visible to all waves
      if (it + 1 < n_it) loadregs((it + 1) * 64);  // issue-early for next tile

      // ---- QK^T: D[q][t] per 16-wide t-tile ----
      f32x4 st[2][4];
      __builtin_amdgcn_s_setprio(1);
#pragma unroll
      for (int tt = 0; tt < 4; ++tt) {
        f32x4 c0 = zero4, c1 = zero4;
        const int krow = (tt * 16 + l15) * 192;
#pragma unroll
        for (int c = 0; c < 6; ++c) {
          bf16x8 kf = *(const bf16x8*)&Kt[krow + (((c * 4 + lg) ^ sw) << 3)];
          c0 = __builtin_amdgcn_mfma_f32_16x16x32_bf16(qf[0][c], kf, c0, 0, 0, 0);
          c1 = __builtin_amdgcn_mfma_f32_16x16x32_bf16(qf[1][c], kf, c1, 0, 0, 0);
        }
        st[0][tt] = c0; st[1][tt] = c1;
      }
      __builtin_amdgcn_s_setprio(0);

      // ---- online softmax (fp32), per m-fragment ----
      const bool domask = (t0 + 63 > qrow_base);
#pragma unroll
      for (int m = 0; m < 2; ++m) {
        float mt[4] = {-1e30f, -1e30f, -1e30f, -1e30f};
#pragma unroll
        for (int tt = 0; tt < 4; ++tt) {
          int tg = t0 + tt * 16 + l15;
#pragma unroll
          for (int i = 0; i < 4; ++i) {
            float v = st[m][tt][i] * scale;
            if (domask) {
              int qg = qrow_base + m * 16 + lg * 4 + i;
              v = (tg > qg) ? -1e30f : v;
            }
            st[m][tt][i] = v;
            mt[i] = fmaxf(mt[i], v);
          }
        }
#pragma unroll
        for (int off = 1; off < 16; off <<= 1)
#pragma unroll
          for (int i = 0; i < 4; ++i) mt[i] = fmaxf(mt[i], __shfl_xor(mt[i], off, 64));

        float al[4], ps[4];
#pragma unroll
        for (int i = 0; i < 4; ++i) {
          float mn = fmaxf(m_r[m][i], mt[i]);
          al[i] = __expf(m_r[m][i] - mn);
          m_r[m][i] = mn;
          ps[i] = 0.f;
        }
#pragma unroll
        for (int tt = 0; tt < 4; ++tt)
#pragma unroll
          for (int i = 0; i < 4; ++i) {
            float p = __expf(st[m][tt][i] - m_r[m][i]);
            st[m][tt][i] = p;
            ps[i] += p;
          }
#pragma unroll
        for (int off = 1; off < 16; off <<= 1)
#pragma unroll
          for (int i = 0; i < 4; ++i) ps[i] += __shfl_xor(ps[i], off, 64);
#pragma unroll
        for (int i = 0; i < 4; ++i) s_r[m][i] = s_r[m][i] * al[i] + ps[i];

        // P -> per-wave LDS [q][t] (b16 scalar; per-wave -> no block barrier)
#pragma unroll
        for (int tt = 0; tt < 4; ++tt)
#pragma unroll
          for (int i = 0; i < 4; ++i)
            Pl[w][(m * 16 + lg * 4 + i) * 72 + tt * 16 + l15] = f2b(st[m][tt][i]);

#pragma unroll
        for (int vt = 0; vt < 8; ++vt)
#pragma unroll
          for (int i = 0; i < 4; ++i) o[m][vt][i] *= al[i];
      }

      // ---- PV: A = P[q][t], B = V^T[v][t] ----
      bf16x8 pa[2][2];
#pragma unroll
      for (int m = 0; m < 2; ++m)
#pragma unroll
        for (int ks = 0; ks < 2; ++ks)
          pa[m][ks] = *(const bf16x8*)&Pl[w][(m * 16 + l15) * 72 + ks * 32 + lg * 8];
      __builtin_amdgcn_s_setprio(1);
#pragma unroll
      for (int vt = 0; vt < 8; ++vt) {
        bf16x8 b0 = *(const bf16x8*)&Vt[(vt * 16 + l15) * 72 + lg * 8];
        bf16x8 b1 = *(const bf16x8*)&Vt[(vt * 16 + l15) * 72 + 32 + lg * 8];
#pragma unroll
        for (int m = 0; m < 2; ++m) {
          o[m][vt] = __builtin_amdgcn_mfma_f32_16x16x32_bf16(pa[m][0], b0, o[m][vt], 0, 0, 0);
          o[m][vt] = __builtin_amdgcn_mfma_f32_16x16x32_bf16(pa[m][1], b1, o[m][vt], 0, 0, 0);
        }
      }
      __builtin_amdgcn_s_setprio(0);
      __syncthreads();  // all waves done reading Kt/Vt; next writelds may proceed
    }

    // ---- normalize + store this q-tile ----
#pragma unroll
    for (int m = 0; m < 2; ++m)
#pragma unroll
      for (int vt = 0; vt < 8; ++vt)
#pragma unroll
        for (int i = 0; i < 4; ++i) {
          int qg = qrow_base + m * 16 + lg * 4 + i;
          int col = h * 128 + vt * 16 + l15;
          ao[(size_t)qg * (NH * 128) + col] = f2b(o[m][vt][i] / s_r[m][i]);
        }
  }
}

extern "C" void kernel_launch(void* const* d_in, const int* in_sizes, int n_in,
                              void* d_out, int out_size, void* d_ws, size_t ws_size,
                              hipStream_t stream) {
  (void)in_sizes; (void)n_in; (void)out_size; (void)ws_size;
  // inputs: 0=positions(arange, unused), 1=hidden_states, 2=Wq, 3=Wkv_a, 4=ln_w, 5=Wkv_b, 6=Wo
  const float* hs = (const float*)d_in[1];
  const float* Wq = (const float*)d_in[2];
  const float* Wkva = (const float*)d_in[3];
  const float* lnw = (const float*)d_in[4];
  const float* Wkvb = (const float*)d_in[5];
  const float* Wo = (const float*)d_in[6];
  float* out = (float*)d_out;
  char* ws = (char*)d_ws;

  constexpr size_t OFF_HSBF = 0;                                    // 2048x4096 bf16
  constexpr size_t OFF_WQT = OFF_HSBF + (size_t)2048 * 4096 * 2;    // 6144x4096 bf16
  constexpr size_t OFF_WKVAT = OFF_WQT + (size_t)6144 * 4096 * 2;   // 640x4096 bf16
  constexpr size_t OFF_WKVBT = OFF_WKVAT + (size_t)640 * 4096 * 2;  // 8192x512 bf16
  constexpr size_t OFF_WOT = OFF_WKVBT + (size_t)8192 * 512 * 2;    // 4096x4096 bf16
  constexpr size_t OFF_Q = OFF_WOT + (size_t)4096 * 4096 * 2;       // 2048x6144 bf16
  constexpr size_t OFF_CKV = OFF_Q + (size_t)2048 * 6144 * 2;       // 2048x640 f32
  constexpr size_t OFF_CKVN = OFF_CKV + (size_t)2048 * 640 * 4;     // 2048x512 bf16
  constexpr size_t OFF_KR = OFF_CKVN + (size_t)2048 * 512 * 2;      // 2048x64 bf16
  constexpr size_t OFF_KV = OFF_KR + (size_t)2048 * 64 * 2;         // 2048x8192 bf16
  constexpr size_t OFF_VT = OFF_KV + (size_t)2048 * 8192 * 2;       // 32x128x2048 bf16
  constexpr size_t OFF_AO = OFF_VT + (size_t)32 * 128 * 2048 * 2;   // 2048x4096 bf16

  unsigned short* hs_bf = (unsigned short*)(ws + OFF_HSBF);
  unsigned short* WqT = (unsigned short*)(ws + OFF_WQT);
  unsigned short* WkvaT = (unsigned short*)(ws + OFF_WKVAT);
  unsigned short* WkvbT = (unsigned short*)(ws + OFF_WKVBT);
  unsigned short* WoT = (unsigned short*)(ws + OFF_WOT);
  unsigned short* qbuf = (unsigned short*)(ws + OFF_Q);
  float* ckv = (float*)(ws + OFF_CKV);
  unsigned short* ckvn = (unsigned short*)(ws + OFF_CKVN);
  unsigned short* kr = (unsigned short*)(ws + OFF_KR);
  unsigned short* kvbuf = (unsigned short*)(ws + OFF_KV);
  unsigned short* vT = (unsigned short*)(ws + OFF_VT);
  unsigned short* ao = (unsigned short*)(ws + OFF_AO);

  convk<<<dim3(8192), 256, 0, stream>>>(hs, hs_bf, 2048 * 4096 / 4);
  tconv<<<dim3(64, 96), 256, 0, stream>>>(Wq, WqT, 4096, 6144, 6144);
  tconv<<<dim3(64, 10), 256, 0, stream>>>(Wkva, WkvaT, 4096, 576, 640);
  tconv<<<dim3(8, 128), 256, 0, stream>>>(Wkvb, WkvbT, 512, 8192, 8192);
  tconv<<<dim3(64, 64), 256, 0, stream>>>(Wo, WoT, 4096, 4096, 4096);

  gemm_bt<unsigned short><<<dim3(16 * 48), 256, 0, stream>>>(hs_bf, WqT, qbuf, 2048, 6144, 4096);
  gemm_bt<float><<<dim3(16 * 5), 256, 0, stream>>>(hs_bf, WkvaT, ckv, 2048, 640, 4096);
  rmsnorm_k<<<dim3(2048), 256, 0, stream>>>(ckv, lnw, ckvn);
  rope_k_k<<<dim3(256), 256, 0, stream>>>(ckv, kr);
  gemm_bt<unsigned short><<<dim3(16 * 64), 256, 0, stream>>>(ckvn, WkvbT, kvbuf, 2048, 8192, 512);
  rope_q_k<<<dim3(8192), 256, 0, stream>>>(qbuf);
  tv_k<<<dim3(32, 2, 32), 256, 0, stream>>>(kvbuf, vT);
  attn_k<<<dim3(8, 32), 256, 0, stream>>>(qbuf, kvbuf, kr, vT, ao);
  gemm_bt<float><<<dim3(16 * 32), 256, 0, stream>>>(ao, WoT, out, 2048, 4096, 4096);
}